// Round 1
// baseline (656.943 us; speedup 1.0000x reference)
//
#include <hip/hip_runtime.h>

// GCN: h1 = relu(conv(x,W1,b1)); h2 = relu(conv(h1,W2,b2)); pooled = segsum(h2,batch); out = pooled@Wlin+blin
// conv(x) = segment_sum(norm * (x@W)[row] -> col) + b, with self-loops folded into per-node init.

#define TPB 256

__global__ void k_init_deg(float* __restrict__ deg, int N) {
    int i = blockIdx.x * blockDim.x + threadIdx.x;
    if (i < N) deg[i] = 1.0f;  // self-loop weight
}

__global__ void k_deg_scatter(const int* __restrict__ col, const float* __restrict__ w,
                              float* __restrict__ deg, int E) {
    int e = blockIdx.x * blockDim.x + threadIdx.x;
    if (e < E) atomicAdd(&deg[col[e]], w[e]);
}

__global__ void k_dinv(const float* __restrict__ deg, float* __restrict__ dinv, int N) {
    int i = blockIdx.x * blockDim.x + threadIdx.x;
    if (i < N) {
        float d = deg[i];
        dinv[i] = d > 0.0f ? rsqrtf(d) : 0.0f;
    }
}

__global__ void k_norm(const int* __restrict__ row, const int* __restrict__ col,
                       const float* __restrict__ w, const float* __restrict__ dinv,
                       float* __restrict__ norm, int E) {
    int e = blockIdx.x * blockDim.x + threadIdx.x;
    if (e < E) norm[e] = dinv[row[e]] * w[e] * dinv[col[e]];
}

// h1[i][f] = b1[f] + dinv[i]^2 * hx[i][f],  hx[i][f] = (x[i,0:3] @ W1)[f]
__global__ void k_layer1_init(const float* __restrict__ x, const float* __restrict__ W1,
                              const float* __restrict__ b1, const float* __restrict__ dinv,
                              float* __restrict__ hx, float* __restrict__ h1, int N) {
    int t = blockIdx.x * blockDim.x + threadIdx.x;
    int i = t >> 4, f = t & 15;
    if (i >= N) return;
    float x0 = x[i * 3 + 0], x1 = x[i * 3 + 1], x2 = x[i * 3 + 2];
    float v = x0 * W1[0 * 16 + f] + x1 * W1[1 * 16 + f] + x2 * W1[2 * 16 + f];
    hx[i * 16 + f] = v;
    float di = dinv[i];
    h1[i * 16 + f] = b1[f] + di * di * v;
}

// 16 threads per edge (lane = feature): atomics within an edge hit 16 contiguous floats.
__global__ void k_scatter(const int* __restrict__ row, const int* __restrict__ col,
                          const float* __restrict__ norm, const float* __restrict__ hx,
                          float* __restrict__ h, int E) {
    long long t = (long long)blockIdx.x * blockDim.x + threadIdx.x;
    int e = (int)(t >> 4), f = (int)(t & 15);
    if (e >= E) return;
    int r = row[e], c = col[e];
    float v = norm[e] * hx[r * 16 + f];
    atomicAdd(&h[c * 16 + f], v);
}

// hx2[i][f] = (relu(h1[i]) @ W2)[f];  h2[i][f] = b2[f] + dinv[i]^2 * hx2[i][f]
__global__ void k_layer2_init(const float* __restrict__ h1, const float* __restrict__ W2,
                              const float* __restrict__ b2, const float* __restrict__ dinv,
                              float* __restrict__ hx2, float* __restrict__ h2, int N) {
    int t = blockIdx.x * blockDim.x + threadIdx.x;
    int i = t >> 4, f = t & 15;
    if (i >= N) return;
    float v = 0.0f;
#pragma unroll
    for (int k = 0; k < 16; k++) {
        float hk = h1[i * 16 + k];
        hk = hk > 0.0f ? hk : 0.0f;
        v += hk * W2[k * 16 + f];
    }
    hx2[i * 16 + f] = v;
    float di = dinv[i];
    h2[i * 16 + f] = b2[f] + di * di * v;
}

__global__ void k_pool(const float* __restrict__ h2, const int* __restrict__ batch,
                       float* __restrict__ pooled, int N) {
    int t = blockIdx.x * blockDim.x + threadIdx.x;
    int i = t >> 4, f = t & 15;
    if (i >= N) return;
    float v = h2[i * 16 + f];
    v = v > 0.0f ? v : 0.0f;  // relu on h2 applied here
    atomicAdd(&pooled[batch[i] * 16 + f], v);
}

__global__ void k_final(const float* __restrict__ pooled, const float* __restrict__ Wlin,
                        const float* __restrict__ blin, float* __restrict__ out, int G) {
    int t = blockIdx.x * blockDim.x + threadIdx.x;
    int g = t / 7, j = t % 7;
    if (g >= G) return;
    float v = blin[j];
#pragma unroll
    for (int f = 0; f < 16; f++) v += pooled[g * 16 + f] * Wlin[f * 7 + j];
    out[g * 7 + j] = v;
}

static inline int cdiv_i(long long a, long long b) { return (int)((a + b - 1) / b); }

extern "C" void kernel_launch(void* const* d_in, const int* in_sizes, int n_in,
                              void* d_out, int out_size, void* d_ws, size_t ws_size,
                              hipStream_t stream) {
    const float* x     = (const float*)d_in[0];
    const int*   ei    = (const int*)d_in[1];
    const float* ew    = (const float*)d_in[2];
    const int*   batch = (const int*)d_in[3];
    const float* W1    = (const float*)d_in[4];
    const float* b1    = (const float*)d_in[5];
    const float* W2    = (const float*)d_in[6];
    const float* b2    = (const float*)d_in[7];
    const float* Wlin  = (const float*)d_in[8];
    const float* blin  = (const float*)d_in[9];
    float* out = (float*)d_out;

    const int N = in_sizes[0] / 3;
    const int E = in_sizes[2];
    const int G = out_size / 7;
    const int* row = ei;       // edge_index[0]
    const int* col = ei + E;   // edge_index[1]

    float* ws = (float*)d_ws;
    float* deg    = ws;                 // N
    float* dinv   = deg + N;            // N
    float* norm   = dinv + N;           // E
    float* hx     = norm + E;           // N*16  (reused as hx2 for layer 2)
    float* h1     = hx + (size_t)N * 16;   // N*16
    float* h2     = h1 + (size_t)N * 16;   // N*16
    float* pooled = h2 + (size_t)N * 16;   // G*16

    hipMemsetAsync(pooled, 0, (size_t)G * 16 * sizeof(float), stream);

    k_init_deg<<<cdiv_i(N, TPB), TPB, 0, stream>>>(deg, N);
    k_deg_scatter<<<cdiv_i(E, TPB), TPB, 0, stream>>>(col, ew, deg, E);
    k_dinv<<<cdiv_i(N, TPB), TPB, 0, stream>>>(deg, dinv, N);
    k_norm<<<cdiv_i(E, TPB), TPB, 0, stream>>>(row, col, ew, dinv, norm, E);

    // layer 1
    k_layer1_init<<<cdiv_i((long long)N * 16, TPB), TPB, 0, stream>>>(x, W1, b1, dinv, hx, h1, N);
    k_scatter<<<cdiv_i((long long)E * 16, TPB), TPB, 0, stream>>>(row, col, norm, hx, h1, E);

    // layer 2 (relu(h1) folded into init; hx reused as hx2)
    k_layer2_init<<<cdiv_i((long long)N * 16, TPB), TPB, 0, stream>>>(h1, W2, b2, dinv, hx, h2, N);
    k_scatter<<<cdiv_i((long long)E * 16, TPB), TPB, 0, stream>>>(row, col, norm, hx, h2, E);

    // pool (relu(h2) folded) + head
    k_pool<<<cdiv_i((long long)N * 16, TPB), TPB, 0, stream>>>(h2, batch, pooled, N);
    k_final<<<cdiv_i((long long)G * 7, TPB), TPB, 0, stream>>>(pooled, Wlin, blin, out, G);
}